// Round 1
// 161.419 us; speedup vs baseline: 1.2009x; 1.2009x over previous
//
#include <hip/hip_runtime.h>

typedef unsigned short u16;
typedef __attribute__((ext_vector_type(8))) short bf16x8;  // 8 bf16 in 4 VGPRs
typedef __attribute__((ext_vector_type(4))) float f32x4;

constexpr int BATCH = 8192;
constexpr int UNITS = 1024;
constexpr int K2    = 2048;   // combined K  ([x | h_prev])
constexpr int N4    = 4096;   // 4*UNITS gate columns
constexpr int BK    = 64;     // K-tile
constexpr int BM    = 256;    // batch rows per block
constexpr int BN    = 256;    // gate cols per block
constexpr int NKT   = K2 / BK;        // 32
constexpr int ASZ   = BM * BK;        // 16384 u16 = 32 KB per A buffer
constexpr int BSZ   = BN * BK;        // 16384 u16 = 32 KB per B buffer

__device__ __forceinline__ u16 f2bf(float f) {
  unsigned u = __float_as_uint(f);
  u += 0x7fffu + ((u >> 16) & 1u);   // round-to-nearest-even
  return (u16)(u >> 16);
}

__device__ __forceinline__ void async_copy16(const void* g, void* l) {
  __builtin_amdgcn_global_load_lds(
      (const __attribute__((address_space(1))) void*)g,
      (__attribute__((address_space(3))) void*)l, 16, 0, 0);
}

// ---------------------------------------------------------------------------
// Fused cast kernel (unchanged — BW-bound near roofline, conflict-free).
//   blocks [0, 2048):    B pack/transpose/permute  (64n x 64k tile per block)
//   blocks [2048, 6144): A = [x | h_prev] bf16 pack (grid-stride float4)
// B layout: bf16 [4096 p][2048 k], B[p][k] = src[k][oc(p)],
//   oc(p) = jn*1024 + (p>>6)*16 + (p&15), jn = (p>>4)&3  → any 64-aligned
//   group of B rows = the 4 gates of the same 16 units.
// ---------------------------------------------------------------------------
__global__ __launch_bounds__(256) void cast_fused_kernel(
    const float* __restrict__ x, const float* __restrict__ h,
    const float* __restrict__ W, const float* __restrict__ U,
    u16* __restrict__ A, u16* __restrict__ B) {
  const int tid = threadIdx.x;
  if (blockIdx.x < 2048) {
    __shared__ float lds[64 * 69];
    const int bid = blockIdx.x;
    const int nb  = bid & 63;
    const int kb  = bid >> 6;
    const int n0  = nb * 64;
    const int k0  = kb * 64;
    const int jn  = n0 >> 10;
    const int q0  = (n0 & 1023) >> 4;
    const float* src = (k0 < UNITS) ? (W + (size_t)k0 * N4)
                                    : (U + (size_t)(k0 - UNITS) * N4);
    {
      const int kk  = tid >> 4;
      const int nn4 = (tid & 15) * 4;
#pragma unroll
      for (int r = 0; r < 4; ++r) {
        const int k = kk + r * 16;
        float4 v = *reinterpret_cast<const float4*>(&src[(size_t)k * N4 + n0 + nn4]);
        lds[k * 69 + nn4 + 0] = v.x;
        lds[k * 69 + nn4 + 1] = v.y;
        lds[k * 69 + nn4 + 2] = v.z;
        lds[k * 69 + nn4 + 3] = v.w;
      }
    }
    __syncthreads();
    {
      const int kk4 = (tid & 15) * 4;
#pragma unroll
      for (int pass = 0; pass < 4; ++pass) {
        const int rr  = (tid >> 4) + pass * 16;
        const int q   = q0 + (rr >> 4);
        const int low = rr & 15;
        const int p   = q * 64 + jn * 16 + low;
        union { ushort4 u4; u16 s[4]; } o;
#pragma unroll
        for (int j = 0; j < 4; ++j) o.s[j] = f2bf(lds[(kk4 + j) * 69 + rr]);
        *reinterpret_cast<ushort4*>(&B[(size_t)p * K2 + k0 + kk4]) = o.u4;
      }
    }
  } else {
    const int t0 = (blockIdx.x - 2048) * 256 + tid;
    const int stride = 4096 * 256;
#pragma unroll
    for (int s = 0; s < 4; ++s) {
      const int g = t0 + s * stride;
      const int idx = g * 4;
      const int b = idx >> 11;
      const int k = idx & 2047;
      const float* src = (k < UNITS) ? (x + (size_t)b * UNITS + k)
                                     : (h + (size_t)b * UNITS + (k - UNITS));
      float4 v = *reinterpret_cast<const float4*>(src);
      union { ushort4 u4; u16 sv[4]; } o;
      o.sv[0] = f2bf(v.x); o.sv[1] = f2bf(v.y);
      o.sv[2] = f2bf(v.z); o.sv[3] = f2bf(v.w);
      *reinterpret_cast<ushort4*>(A + idx) = o.u4;
    }
  }
}

// ---------------------------------------------------------------------------
// 256x256 phase-pipelined GEMM + fused peephole LSTM epilogue.
// 8 waves (2M x 4N), per-wave 128x64 output, acc[8][4] (jn = gate).
// LDS: A triple-buffered (3x32KB) + B double-buffered (2x32KB) = 160 KB.
// Per K-tile: 4 phases of {stage-issue | ds_read frags | s_barrier |
//   setprio(1) 16 MFMA setprio(0) | s_barrier}.  Staging: B(kt+1) at
//   phases 0-1 into B-buf^1, A(kt+2) at phases 2-3 into A-buf (kt+2)%3.
// One counted s_waitcnt vmcnt(4) per K-tile (A(kt+2)'s 4 loads stay in
// flight across the barrier) — never a full drain until the tail.
// Swizzle (proven 0-conflict): LDS row = 64 u16 = 8 slots of 16B; k-group g
// of row r at slot g^(r&7); staging pre-swizzles the GLOBAL address
// (lane fetches k-group (t&7)^((t>>3)&7)), LDS dest stays lane-linear.
// ---------------------------------------------------------------------------
__global__ __launch_bounds__(512, 2) void lstm_gemm_kernel(
    const u16* __restrict__ A, const u16* __restrict__ B,
    const float* __restrict__ bias, const float* __restrict__ c_prev,
    const float* __restrict__ pf, const float* __restrict__ pi,
    const float* __restrict__ po,
    float* __restrict__ out_h, float* __restrict__ out_c) {
  __shared__ u16 lds[3 * ASZ + 2 * BSZ];   // 163840 B exactly
  u16* const Asb = lds;            // 3 A buffers
  u16* const Bsb = lds + 3 * ASZ;  // 2 B buffers

  const int tid  = threadIdx.x;
  const int lane = tid & 63;
  const int wave = tid >> 6;
  const int quad = lane >> 4;
  const int c    = lane & 15;

  // XCD-aware bijective swizzle (nwg = 512, 512 % 8 == 0): each XCD gets
  // 64 consecutive tiles = 4 A-panels (4 MB, L2-resident) x all 16 B-panels.
  int lin = blockIdx.y * 16 + blockIdx.x;
  lin = (lin & 7) * 64 + (lin >> 3);
  const int m0 = (lin >> 4) * BM;
  const int n0 = (lin & 15) * BN;

  const int wm = (wave >> 2) * 128;   // 2 M-wave-groups
  const int wn = (wave & 3) * 64;     // 4 N-wave-groups

  // ---- staging setup: round i covers rows i*64 + (tid>>3), 8 lanes/row ----
  const int g8   = ((tid & 7) ^ ((tid >> 3) & 7)) * 8;  // pre-swizzled k-group
  const int rowa = tid >> 3;
  const u16* gA = A + (size_t)(m0 + rowa) * K2 + g8;
  const u16* gB = B + (size_t)(n0 + rowa) * K2 + g8;
  const int ldst = tid * 8;    // u16 idx: dest = buf_base + i*4096 + ldst

  // ---- fragment read offsets (slot = (ks*4+quad)^(c&7), row&7 == c&7) ----
  const int sl0   = (quad ^ (c & 7)) * 8;
  const int sl1   = ((4 + quad) ^ (c & 7)) * 8;
  const int aoff0 = (wm + c) * 64 + sl0;   // + jm*1024
  const int aoff1 = (wm + c) * 64 + sl1;
  const int boff0 = (wn + c) * 64 + sl0;   // + jn*1024
  const int boff1 = (wn + c) * 64 + sl1;

  f32x4 acc[8][4] = {};

  // ---- prologue: A(0)->Abuf0, B(0)->Bbuf0, A(1)->Abuf1 (12 loads) ----
#pragma unroll
  for (int i = 0; i < 4; ++i)
    async_copy16(gA + (size_t)i * 64 * K2, &Asb[i * 4096 + ldst]);
#pragma unroll
  for (int i = 0; i < 4; ++i)
    async_copy16(gB + (size_t)i * 64 * K2, &Bsb[i * 4096 + ldst]);
#pragma unroll
  for (int i = 0; i < 4; ++i)
    async_copy16(gA + (size_t)i * 64 * K2 + BK, &Asb[ASZ + i * 4096 + ldst]);
  asm volatile("s_waitcnt vmcnt(4)" ::: "memory");   // A(0),B(0) landed
  __builtin_amdgcn_s_barrier();
  __builtin_amdgcn_sched_barrier(0);

  int curA = 0;
#pragma unroll 1
  for (int kt = 0; kt < NKT; ++kt) {
    const u16* as = &Asb[curA * ASZ];
    const u16* bs = &Bsb[(kt & 1) * BSZ];
    const int stgA = (curA == 0) ? 2 : curA - 1;    // (kt+2) % 3
    u16* sA = &Asb[stgA * ASZ];
    u16* sB = &Bsb[((kt + 1) & 1) * BSZ];
    const bool doB = (kt < NKT - 1);
    const bool doA = (kt < NKT - 2);
    const size_t okB = (size_t)(kt + 1) * BK;
    const size_t okA = (size_t)(kt + 2) * BK;

    bf16x8 bfr[2][4];   // B frags for the whole K-tile (reused phases 1-3)
#pragma unroll
    for (int ph = 0; ph < 4; ++ph) {
      // -- stage issues: 2 global_load_lds per thread per phase --
      if (ph == 0 && doB) {
        async_copy16(gB + okB,                     sB + ldst);
        async_copy16(gB + okB + (size_t)64 * K2,   sB + 4096 + ldst);
      }
      if (ph == 1 && doB) {
        async_copy16(gB + okB + (size_t)128 * K2,  sB + 8192 + ldst);
        async_copy16(gB + okB + (size_t)192 * K2,  sB + 12288 + ldst);
      }
      if (ph == 2 && doA) {
        async_copy16(gA + okA,                     sA + ldst);
        async_copy16(gA + okA + (size_t)64 * K2,   sA + 4096 + ldst);
      }
      if (ph == 3 && doA) {
        async_copy16(gA + okA + (size_t)128 * K2,  sA + 8192 + ldst);
        async_copy16(gA + okA + (size_t)192 * K2,  sA + 12288 + ldst);
      }
      // -- LDS -> register fragments --
      if (ph == 0) {
#pragma unroll
        for (int jn = 0; jn < 4; ++jn) {
          bfr[0][jn] = *(const bf16x8*)(bs + boff0 + jn * 1024);
          bfr[1][jn] = *(const bf16x8*)(bs + boff1 + jn * 1024);
        }
      }
      bf16x8 af0[2], af1[2];
#pragma unroll
      for (int jm = 0; jm < 2; ++jm) {
        af0[jm] = *(const bf16x8*)(as + aoff0 + (2 * ph + jm) * 1024);
        af1[jm] = *(const bf16x8*)(as + aoff1 + (2 * ph + jm) * 1024);
      }
      // -- counted vmcnt once per K-tile: kt+1 landed, A(kt+2) in flight --
      if (ph == 3) {
        if (kt < NKT - 2)       asm volatile("s_waitcnt vmcnt(4)" ::: "memory");
        else if (kt == NKT - 2) asm volatile("s_waitcnt vmcnt(0)" ::: "memory");
      }
      __builtin_amdgcn_s_barrier();
      __builtin_amdgcn_sched_barrier(0);
      __builtin_amdgcn_s_setprio(1);
#pragma unroll
      for (int jm = 0; jm < 2; ++jm)
#pragma unroll
        for (int jn = 0; jn < 4; ++jn)
          acc[2 * ph + jm][jn] = __builtin_amdgcn_mfma_f32_16x16x32_bf16(
              af0[jm], bfr[0][jn], acc[2 * ph + jm][jn], 0, 0, 0);
#pragma unroll
      for (int jm = 0; jm < 2; ++jm)
#pragma unroll
        for (int jn = 0; jn < 4; ++jn)
          acc[2 * ph + jm][jn] = __builtin_amdgcn_mfma_f32_16x16x32_bf16(
              af1[jm], bfr[1][jn], acc[2 * ph + jm][jn], 0, 0, 0);
      __builtin_amdgcn_s_setprio(0);
      if (!(ph == 3 && kt == NKT - 1)) {
        __builtin_amdgcn_s_barrier();
        __builtin_amdgcn_sched_barrier(0);
      }
    }
    curA = (curA == 2) ? 0 : curA + 1;
  }

  // ---- fused peephole-LSTM epilogue -------------------------------------
  const int u = ((n0 + wn) >> 2) + c;
  const float bf_ = bias[u];
  const float bi_ = bias[UNITS + u];
  const float bc_ = bias[2 * UNITS + u];
  const float bo_ = bias[3 * UNITS + u];
  const float pfv = pf[u], piv = pi[u], pov = po[u];
  const int mbase = m0 + wm + quad * 4;
#pragma unroll
  for (int jm = 0; jm < 8; ++jm) {
#pragma unroll
    for (int r = 0; r < 4; ++r) {
      const int b = mbase + jm * 16 + r;
      const float cp = c_prev[(size_t)b * UNITS + u];
      const float zf = acc[jm][0][r] + bf_ + pfv * cp;
      const float zi = acc[jm][1][r] + bi_ + piv * cp;
      const float zc = acc[jm][2][r] + bc_;
      const float zo = acc[jm][3][r] + bo_;
      const float fg = 1.f / (1.f + __expf(-zf));
      const float ig = 1.f / (1.f + __expf(-zi));
      const float ct = 1.f - 2.f / (__expf(2.f * zc) + 1.f);   // tanh, NaN-safe
      const float cn = fg * cp + ig * ct;
      const float og = 1.f / (1.f + __expf(-(zo + pov * cn)));
      const float hn = og * (1.f - 2.f / (__expf(2.f * cn) + 1.f));
      out_h[(size_t)b * UNITS + u] = hn;
      out_c[(size_t)b * UNITS + u] = cn;
    }
  }
}

// ---------------------------------------------------------------------------
extern "C" void kernel_launch(void* const* d_in, const int* in_sizes, int n_in,
                              void* d_out, int out_size, void* d_ws, size_t ws_size,
                              hipStream_t stream) {
  const float* x      = (const float*)d_in[0];   // [8192,1024]
  const float* c_prev = (const float*)d_in[1];   // [8192,1024]
  const float* h_prev = (const float*)d_in[2];   // [8192,1024]
  const float* W      = (const float*)d_in[3];   // [1024,4096]
  const float* U      = (const float*)d_in[4];   // [1024,4096]
  const float* bias   = (const float*)d_in[5];   // [4096]
  const float* pf     = (const float*)d_in[6];   // [1024]
  const float* pi     = (const float*)d_in[7];
  const float* po     = (const float*)d_in[8];
  float* out_h = (float*)d_out;
  float* out_c = out_h + (size_t)BATCH * UNITS;

  u16* Abf = (u16*)d_ws;                           // 32 MB
  u16* Bbf = Abf + (size_t)BATCH * K2;             // 16 MB

  cast_fused_kernel<<<6144, 256, 0, stream>>>(x, h_prev, W, U, Abf, Bbf);
  lstm_gemm_kernel<<<dim3(N4 / BN, BATCH / BM), 512, 0, stream>>>(
      Abf, Bbf, bias, c_prev, pf, pi, po, out_h, out_c);
}

// Round 2
// 160.439 us; speedup vs baseline: 1.2082x; 1.0061x over previous
//
#include <hip/hip_runtime.h>

typedef unsigned short u16;
typedef __attribute__((ext_vector_type(8))) short bf16x8;  // 8 bf16 in 4 VGPRs
typedef __attribute__((ext_vector_type(4))) float f32x4;

constexpr int BATCH = 8192;
constexpr int UNITS = 1024;
constexpr int K2    = 2048;   // combined K  ([x | h_prev])
constexpr int N4    = 4096;   // 4*UNITS gate columns
constexpr int BK    = 64;     // K-tile
constexpr int BM    = 256;    // batch rows per block
constexpr int BN    = 256;    // gate cols per block
constexpr int NKT   = K2 / BK;        // 32
constexpr int ASZ   = BM * BK;        // 16384 u16 = 32 KB per A buffer
constexpr int BSZ   = BN * BK;        // 16384 u16 = 32 KB per B buffer

__device__ __forceinline__ u16 f2bf(float f) {
  unsigned u = __float_as_uint(f);
  u += 0x7fffu + ((u >> 16) & 1u);   // round-to-nearest-even
  return (u16)(u >> 16);
}

__device__ __forceinline__ void async_copy16(const void* g, void* l) {
  __builtin_amdgcn_global_load_lds(
      (const __attribute__((address_space(1))) void*)g,
      (__attribute__((address_space(3))) void*)l, 16, 0, 0);
}

// ---------------------------------------------------------------------------
// Fused cast kernel (unchanged — BW-bound near roofline, conflict-free).
//   blocks [0, 2048):    B pack/transpose/permute  (64n x 64k tile per block)
//   blocks [2048, 6144): A = [x | h_prev] bf16 pack (grid-stride float4)
// B layout: bf16 [4096 p][2048 k], B[p][k] = src[k][oc(p)],
//   oc(p) = jn*1024 + (p>>6)*16 + (p&15), jn = (p>>4)&3  → any 64-aligned
//   group of B rows = the 4 gates of the same 16 units.
// ---------------------------------------------------------------------------
__global__ __launch_bounds__(256) void cast_fused_kernel(
    const float* __restrict__ x, const float* __restrict__ h,
    const float* __restrict__ W, const float* __restrict__ U,
    u16* __restrict__ A, u16* __restrict__ B) {
  const int tid = threadIdx.x;
  if (blockIdx.x < 2048) {
    __shared__ float lds[64 * 69];
    const int bid = blockIdx.x;
    const int nb  = bid & 63;
    const int kb  = bid >> 6;
    const int n0  = nb * 64;
    const int k0  = kb * 64;
    const int jn  = n0 >> 10;
    const int q0  = (n0 & 1023) >> 4;
    const float* src = (k0 < UNITS) ? (W + (size_t)k0 * N4)
                                    : (U + (size_t)(k0 - UNITS) * N4);
    {
      const int kk  = tid >> 4;
      const int nn4 = (tid & 15) * 4;
#pragma unroll
      for (int r = 0; r < 4; ++r) {
        const int k = kk + r * 16;
        float4 v = *reinterpret_cast<const float4*>(&src[(size_t)k * N4 + n0 + nn4]);
        lds[k * 69 + nn4 + 0] = v.x;
        lds[k * 69 + nn4 + 1] = v.y;
        lds[k * 69 + nn4 + 2] = v.z;
        lds[k * 69 + nn4 + 3] = v.w;
      }
    }
    __syncthreads();
    {
      const int kk4 = (tid & 15) * 4;
#pragma unroll
      for (int pass = 0; pass < 4; ++pass) {
        const int rr  = (tid >> 4) + pass * 16;
        const int q   = q0 + (rr >> 4);
        const int low = rr & 15;
        const int p   = q * 64 + jn * 16 + low;
        union { ushort4 u4; u16 s[4]; } o;
#pragma unroll
        for (int j = 0; j < 4; ++j) o.s[j] = f2bf(lds[(kk4 + j) * 69 + rr]);
        *reinterpret_cast<ushort4*>(&B[(size_t)p * K2 + k0 + kk4]) = o.u4;
      }
    }
  } else {
    const int t0 = (blockIdx.x - 2048) * 256 + tid;
    const int stride = 4096 * 256;
#pragma unroll
    for (int s = 0; s < 4; ++s) {
      const int g = t0 + s * stride;
      const int idx = g * 4;
      const int b = idx >> 11;
      const int k = idx & 2047;
      const float* src = (k < UNITS) ? (x + (size_t)b * UNITS + k)
                                     : (h + (size_t)b * UNITS + (k - UNITS));
      float4 v = *reinterpret_cast<const float4*>(src);
      union { ushort4 u4; u16 sv[4]; } o;
      o.sv[0] = f2bf(v.x); o.sv[1] = f2bf(v.y);
      o.sv[2] = f2bf(v.z); o.sv[3] = f2bf(v.w);
      *reinterpret_cast<ushort4*>(A + idx) = o.u4;
    }
  }
}

// ---------------------------------------------------------------------------
// 256x256 phase-pipelined GEMM + fused peephole LSTM epilogue.
// 8 waves (2M x 4N), per-wave 128x64 output, acc[8][4] (jn = gate).
// LDS: A triple-buffered (3x32KB) + B double-buffered (2x32KB) = 160 KB.
// Per K-tile: 4 phases of {stage-issue | ds_read frags | s_barrier |
//   setprio(1) 16 MFMA setprio(0) | s_barrier}.  Staging: B(kt+1) at
//   phases 0-1 into B-buf^1, A(kt+2) at phases 2-3 into A-buf (kt+2)%3.
// One counted s_waitcnt vmcnt(4) per K-tile (A(kt+2)'s 4 loads stay in
// flight across the barrier) — never a full drain until the tail.
// NO sched_barrier pins (R2 fix, m141 lesson): barriers + the vmcnt
// "memory" clobber give all the ordering correctness needs; the compiler
// is free to hoist next-phase addr-calc/ds_read issue into MFMA clusters.
// Swizzle (proven 0-conflict): LDS row = 64 u16 = 8 slots of 16B; k-group g
// of row r at slot g^(r&7); staging pre-swizzles the GLOBAL address
// (lane fetches k-group (t&7)^((t>>3)&7)), LDS dest stays lane-linear.
// ---------------------------------------------------------------------------
__global__ __launch_bounds__(512, 2) void lstm_gemm_kernel(
    const u16* __restrict__ A, const u16* __restrict__ B,
    const float* __restrict__ bias, const float* __restrict__ c_prev,
    const float* __restrict__ pf, const float* __restrict__ pi,
    const float* __restrict__ po,
    float* __restrict__ out_h, float* __restrict__ out_c) {
  __shared__ u16 lds[3 * ASZ + 2 * BSZ];   // 163840 B exactly
  u16* const Asb = lds;            // 3 A buffers
  u16* const Bsb = lds + 3 * ASZ;  // 2 B buffers

  const int tid  = threadIdx.x;
  const int lane = tid & 63;
  const int wave = tid >> 6;
  const int quad = lane >> 4;
  const int c    = lane & 15;

  // XCD-aware bijective swizzle (nwg = 512, 512 % 8 == 0): each XCD gets
  // 64 consecutive tiles = 4 A-panels (4 MB, L2-resident) x all 16 B-panels.
  int lin = blockIdx.y * 16 + blockIdx.x;
  lin = (lin & 7) * 64 + (lin >> 3);
  const int m0 = (lin >> 4) * BM;
  const int n0 = (lin & 15) * BN;

  const int wm = (wave >> 2) * 128;   // 2 M-wave-groups
  const int wn = (wave & 3) * 64;     // 4 N-wave-groups

  // ---- staging setup: round i covers rows i*64 + (tid>>3), 8 lanes/row ----
  const int g8   = ((tid & 7) ^ ((tid >> 3) & 7)) * 8;  // pre-swizzled k-group
  const int rowa = tid >> 3;
  const u16* gA = A + (size_t)(m0 + rowa) * K2 + g8;
  const u16* gB = B + (size_t)(n0 + rowa) * K2 + g8;
  const int ldst = tid * 8;    // u16 idx: dest = buf_base + i*4096 + ldst

  // ---- fragment read offsets (slot = (ks*4+quad)^(c&7), row&7 == c&7) ----
  const int sl0   = (quad ^ (c & 7)) * 8;
  const int sl1   = ((4 + quad) ^ (c & 7)) * 8;
  const int aoff0 = (wm + c) * 64 + sl0;   // + jm*1024
  const int aoff1 = (wm + c) * 64 + sl1;
  const int boff0 = (wn + c) * 64 + sl0;   // + jn*1024
  const int boff1 = (wn + c) * 64 + sl1;

  f32x4 acc[8][4] = {};

  // ---- prologue: A(0)->Abuf0, B(0)->Bbuf0, A(1)->Abuf1 (12 loads) ----
#pragma unroll
  for (int i = 0; i < 4; ++i)
    async_copy16(gA + (size_t)i * 64 * K2, &Asb[i * 4096 + ldst]);
#pragma unroll
  for (int i = 0; i < 4; ++i)
    async_copy16(gB + (size_t)i * 64 * K2, &Bsb[i * 4096 + ldst]);
#pragma unroll
  for (int i = 0; i < 4; ++i)
    async_copy16(gA + (size_t)i * 64 * K2 + BK, &Asb[ASZ + i * 4096 + ldst]);
  asm volatile("s_waitcnt vmcnt(4)" ::: "memory");   // A(0),B(0) landed
  __builtin_amdgcn_s_barrier();

  int curA = 0;
#pragma unroll 2
  for (int kt = 0; kt < NKT; ++kt) {
    const u16* as = &Asb[curA * ASZ];
    const u16* bs = &Bsb[(kt & 1) * BSZ];
    const int stgA = (curA == 0) ? 2 : curA - 1;    // (kt+2) % 3
    u16* sA = &Asb[stgA * ASZ];
    u16* sB = &Bsb[((kt + 1) & 1) * BSZ];
    const bool doB = (kt < NKT - 1);
    const bool doA = (kt < NKT - 2);
    const size_t okB = (size_t)(kt + 1) * BK;
    const size_t okA = (size_t)(kt + 2) * BK;

    bf16x8 bfr[2][4];   // B frags for the whole K-tile (reused phases 1-3)
#pragma unroll
    for (int ph = 0; ph < 4; ++ph) {
      // -- stage issues: 2 global_load_lds per thread per phase --
      if (ph == 0 && doB) {
        async_copy16(gB + okB,                     sB + ldst);
        async_copy16(gB + okB + (size_t)64 * K2,   sB + 4096 + ldst);
      }
      if (ph == 1 && doB) {
        async_copy16(gB + okB + (size_t)128 * K2,  sB + 8192 + ldst);
        async_copy16(gB + okB + (size_t)192 * K2,  sB + 12288 + ldst);
      }
      if (ph == 2 && doA) {
        async_copy16(gA + okA,                     sA + ldst);
        async_copy16(gA + okA + (size_t)64 * K2,   sA + 4096 + ldst);
      }
      if (ph == 3 && doA) {
        async_copy16(gA + okA + (size_t)128 * K2,  sA + 8192 + ldst);
        async_copy16(gA + okA + (size_t)192 * K2,  sA + 12288 + ldst);
      }
      // -- LDS -> register fragments --
      if (ph == 0) {
#pragma unroll
        for (int jn = 0; jn < 4; ++jn) {
          bfr[0][jn] = *(const bf16x8*)(bs + boff0 + jn * 1024);
          bfr[1][jn] = *(const bf16x8*)(bs + boff1 + jn * 1024);
        }
      }
      bf16x8 af0[2], af1[2];
#pragma unroll
      for (int jm = 0; jm < 2; ++jm) {
        af0[jm] = *(const bf16x8*)(as + aoff0 + (2 * ph + jm) * 1024);
        af1[jm] = *(const bf16x8*)(as + aoff1 + (2 * ph + jm) * 1024);
      }
      // -- counted vmcnt once per K-tile: kt+1 landed, A(kt+2) in flight --
      if (ph == 3) {
        if (kt < NKT - 2)       asm volatile("s_waitcnt vmcnt(4)" ::: "memory");
        else if (kt == NKT - 2) asm volatile("s_waitcnt vmcnt(0)" ::: "memory");
      }
      __builtin_amdgcn_s_barrier();
      __builtin_amdgcn_s_setprio(1);
#pragma unroll
      for (int jm = 0; jm < 2; ++jm)
#pragma unroll
        for (int jn = 0; jn < 4; ++jn)
          acc[2 * ph + jm][jn] = __builtin_amdgcn_mfma_f32_16x16x32_bf16(
              af0[jm], bfr[0][jn], acc[2 * ph + jm][jn], 0, 0, 0);
#pragma unroll
      for (int jm = 0; jm < 2; ++jm)
#pragma unroll
        for (int jn = 0; jn < 4; ++jn)
          acc[2 * ph + jm][jn] = __builtin_amdgcn_mfma_f32_16x16x32_bf16(
              af1[jm], bfr[1][jn], acc[2 * ph + jm][jn], 0, 0, 0);
      __builtin_amdgcn_s_setprio(0);
      if (!(ph == 3 && kt == NKT - 1)) {
        __builtin_amdgcn_s_barrier();
      }
    }
    curA = (curA == 2) ? 0 : curA + 1;
  }

  // ---- fused peephole-LSTM epilogue -------------------------------------
  const int u = ((n0 + wn) >> 2) + c;
  const float bf_ = bias[u];
  const float bi_ = bias[UNITS + u];
  const float bc_ = bias[2 * UNITS + u];
  const float bo_ = bias[3 * UNITS + u];
  const float pfv = pf[u], piv = pi[u], pov = po[u];
  const int mbase = m0 + wm + quad * 4;
#pragma unroll
  for (int jm = 0; jm < 8; ++jm) {
#pragma unroll
    for (int r = 0; r < 4; ++r) {
      const int b = mbase + jm * 16 + r;
      const float cp = c_prev[(size_t)b * UNITS + u];
      const float zf = acc[jm][0][r] + bf_ + pfv * cp;
      const float zi = acc[jm][1][r] + bi_ + piv * cp;
      const float zc = acc[jm][2][r] + bc_;
      const float zo = acc[jm][3][r] + bo_;
      const float fg = 1.f / (1.f + __expf(-zf));
      const float ig = 1.f / (1.f + __expf(-zi));
      const float ct = 1.f - 2.f / (__expf(2.f * zc) + 1.f);   // tanh, NaN-safe
      const float cn = fg * cp + ig * ct;
      const float og = 1.f / (1.f + __expf(-(zo + pov * cn)));
      const float hn = og * (1.f - 2.f / (__expf(2.f * cn) + 1.f));
      out_h[(size_t)b * UNITS + u] = hn;
      out_c[(size_t)b * UNITS + u] = cn;
    }
  }
}

// ---------------------------------------------------------------------------
extern "C" void kernel_launch(void* const* d_in, const int* in_sizes, int n_in,
                              void* d_out, int out_size, void* d_ws, size_t ws_size,
                              hipStream_t stream) {
  const float* x      = (const float*)d_in[0];   // [8192,1024]
  const float* c_prev = (const float*)d_in[1];   // [8192,1024]
  const float* h_prev = (const float*)d_in[2];   // [8192,1024]
  const float* W      = (const float*)d_in[3];   // [1024,4096]
  const float* U      = (const float*)d_in[4];   // [1024,4096]
  const float* bias   = (const float*)d_in[5];   // [4096]
  const float* pf     = (const float*)d_in[6];   // [1024]
  const float* pi     = (const float*)d_in[7];
  const float* po     = (const float*)d_in[8];
  float* out_h = (float*)d_out;
  float* out_c = out_h + (size_t)BATCH * UNITS;

  u16* Abf = (u16*)d_ws;                           // 32 MB
  u16* Bbf = Abf + (size_t)BATCH * K2;             // 16 MB

  cast_fused_kernel<<<6144, 256, 0, stream>>>(x, h_prev, W, U, Abf, Bbf);
  lstm_gemm_kernel<<<dim3(N4 / BN, BATCH / BM), 512, 0, stream>>>(
      Abf, Bbf, bias, c_prev, pf, pi, po, out_h, out_c);
}

// Round 3
// 153.742 us; speedup vs baseline: 1.2609x; 1.0436x over previous
//
#include <hip/hip_runtime.h>

typedef unsigned short u16;
typedef __attribute__((ext_vector_type(8))) short bf16x8;  // 8 bf16 in 4 VGPRs
typedef __attribute__((ext_vector_type(4))) float f32x4;

constexpr int BATCH = 8192;
constexpr int UNITS = 1024;
constexpr int K2    = 2048;   // combined K  ([x | h_prev])
constexpr int N4    = 4096;   // 4*UNITS gate columns
constexpr int BK    = 64;     // K-tile
constexpr int BM    = 256;    // batch rows per block
constexpr int BN    = 256;    // gate cols per block
constexpr int NKT   = K2 / BK;        // 32
constexpr int ASZ   = BM * BK;        // 16384 u16 = 32 KB per A buffer
constexpr int BSZ   = BN * BK;        // 16384 u16 = 32 KB per B buffer

__device__ __forceinline__ u16 f2bf(float f) {
  unsigned u = __float_as_uint(f);
  u += 0x7fffu + ((u >> 16) & 1u);   // round-to-nearest-even
  return (u16)(u >> 16);
}

__device__ __forceinline__ void async_copy16(const void* g, void* l) {
  __builtin_amdgcn_global_load_lds(
      (const __attribute__((address_space(1))) void*)g,
      (__attribute__((address_space(3))) void*)l, 16, 0, 0);
}

// ---------------------------------------------------------------------------
// Fused cast kernel (unchanged — BW-bound near roofline, conflict-free).
//   blocks [0, 2048):    B pack/transpose/permute  (64n x 64k tile per block)
//   blocks [2048, 6144): A = [x | h_prev] bf16 pack (grid-stride float4)
// B layout: bf16 [4096 p][2048 k], B[p][k] = src[k][oc(p)],
//   oc(p) = jn*1024 + (p>>6)*16 + (p&15), jn = (p>>4)&3  → any 64-aligned
//   group of B rows = the 4 gates of the same 16 units.
// ---------------------------------------------------------------------------
__global__ __launch_bounds__(256) void cast_fused_kernel(
    const float* __restrict__ x, const float* __restrict__ h,
    const float* __restrict__ W, const float* __restrict__ U,
    u16* __restrict__ A, u16* __restrict__ B) {
  const int tid = threadIdx.x;
  if (blockIdx.x < 2048) {
    __shared__ float lds[64 * 69];
    const int bid = blockIdx.x;
    const int nb  = bid & 63;
    const int kb  = bid >> 6;
    const int n0  = nb * 64;
    const int k0  = kb * 64;
    const int jn  = n0 >> 10;
    const int q0  = (n0 & 1023) >> 4;
    const float* src = (k0 < UNITS) ? (W + (size_t)k0 * N4)
                                    : (U + (size_t)(k0 - UNITS) * N4);
    {
      const int kk  = tid >> 4;
      const int nn4 = (tid & 15) * 4;
#pragma unroll
      for (int r = 0; r < 4; ++r) {
        const int k = kk + r * 16;
        float4 v = *reinterpret_cast<const float4*>(&src[(size_t)k * N4 + n0 + nn4]);
        lds[k * 69 + nn4 + 0] = v.x;
        lds[k * 69 + nn4 + 1] = v.y;
        lds[k * 69 + nn4 + 2] = v.z;
        lds[k * 69 + nn4 + 3] = v.w;
      }
    }
    __syncthreads();
    {
      const int kk4 = (tid & 15) * 4;
#pragma unroll
      for (int pass = 0; pass < 4; ++pass) {
        const int rr  = (tid >> 4) + pass * 16;
        const int q   = q0 + (rr >> 4);
        const int low = rr & 15;
        const int p   = q * 64 + jn * 16 + low;
        union { ushort4 u4; u16 s[4]; } o;
#pragma unroll
        for (int j = 0; j < 4; ++j) o.s[j] = f2bf(lds[(kk4 + j) * 69 + rr]);
        *reinterpret_cast<ushort4*>(&B[(size_t)p * K2 + k0 + kk4]) = o.u4;
      }
    }
  } else {
    const int t0 = (blockIdx.x - 2048) * 256 + tid;
    const int stride = 4096 * 256;
#pragma unroll
    for (int s = 0; s < 4; ++s) {
      const int g = t0 + s * stride;
      const int idx = g * 4;
      const int b = idx >> 11;
      const int k = idx & 2047;
      const float* src = (k < UNITS) ? (x + (size_t)b * UNITS + k)
                                     : (h + (size_t)b * UNITS + (k - UNITS));
      float4 v = *reinterpret_cast<const float4*>(src);
      union { ushort4 u4; u16 sv[4]; } o;
      o.sv[0] = f2bf(v.x); o.sv[1] = f2bf(v.y);
      o.sv[2] = f2bf(v.z); o.sv[3] = f2bf(v.w);
      *reinterpret_cast<ushort4*>(A + idx) = o.u4;
    }
  }
}

// ---------------------------------------------------------------------------
// 256x256 GEMM + fused peephole LSTM epilogue — ONE barrier per K-tile.
// 8 waves (2M x 4N), per-wave 128x64 output, acc[8][4] (jn = gate).
// LDS: A and B double-buffered (4 x 32 KB = 128 KB).
// Per K-tile: {issue 8 global_load_lds for tile kt+1 | read B-frags (8 ds) |
//   software-pipelined: read A-frags(ph+1) ∥ 16 MFMA(ph), ph=0..3 |
//   seam: vmcnt(0) + s_barrier}.
// Correctness: within a tile all ds_reads hit stable buffers and staging
// writes hit the other buffer, so NO intra-tile barriers are needed.  The
// seam's per-thread vmcnt(0) + collective barrier guarantees tile kt+1's
// staged data is LDS-visible to every wave; reads of tile kt are consumed
// (lgkm-waited before their MFMAs) before the seam in program order.
// Loads are issued a full tile (~2800 cyc) before the seam drains them →
// vmcnt(0) is stall-free.  No lockstep: waves drift, so one wave's ds_reads
// overlap another's MFMAs (LDS pipe ∥ matrix pipe), and setprio(1) around
// each MFMA cluster arbitrates in favor of the matrix-busy wave.
// Swizzle (proven 0-conflict): LDS row = 64 u16 = 8 slots of 16B; k-group g
// of row r at slot g^(r&7); staging pre-swizzles the GLOBAL address
// (lane fetches k-group (t&7)^((t>>3)&7)), LDS dest stays lane-linear.
// ---------------------------------------------------------------------------
__global__ __launch_bounds__(512, 2) void lstm_gemm_kernel(
    const u16* __restrict__ A, const u16* __restrict__ B,
    const float* __restrict__ bias, const float* __restrict__ c_prev,
    const float* __restrict__ pf, const float* __restrict__ pi,
    const float* __restrict__ po,
    float* __restrict__ out_h, float* __restrict__ out_c) {
  __shared__ u16 lds[2 * ASZ + 2 * BSZ];   // 131072 B
  u16* const Asb = lds;            // 2 A buffers
  u16* const Bsb = lds + 2 * ASZ;  // 2 B buffers

  const int tid  = threadIdx.x;
  const int lane = tid & 63;
  const int wave = tid >> 6;
  const int quad = lane >> 4;
  const int c    = lane & 15;

  // XCD-aware bijective swizzle (nwg = 512, 512 % 8 == 0): each XCD gets
  // 64 consecutive tiles = 4 A-panels (4 MB, L2-resident) x all 16 B-panels.
  int lin = blockIdx.y * 16 + blockIdx.x;
  lin = (lin & 7) * 64 + (lin >> 3);
  const int m0 = (lin >> 4) * BM;
  const int n0 = (lin & 15) * BN;

  const int wm = (wave >> 2) * 128;   // 2 M-wave-groups
  const int wn = (wave & 3) * 64;     // 4 N-wave-groups

  // ---- staging setup: round i covers rows i*64 + (tid>>3), 8 lanes/row ----
  const int g8   = ((tid & 7) ^ ((tid >> 3) & 7)) * 8;  // pre-swizzled k-group
  const int rowa = tid >> 3;
  const u16* gA = A + (size_t)(m0 + rowa) * K2 + g8;
  const u16* gB = B + (size_t)(n0 + rowa) * K2 + g8;
  const int ldst = tid * 8;    // u16 idx: dest = buf_base + i*4096 + ldst

  // ---- fragment read offsets (slot = (ks*4+quad)^(c&7), row&7 == c&7) ----
  const int sl0   = (quad ^ (c & 7)) * 8;
  const int sl1   = ((4 + quad) ^ (c & 7)) * 8;
  const int aoff0 = (wm + c) * 64 + sl0;   // + jm*1024
  const int aoff1 = (wm + c) * 64 + sl1;
  const int boff0 = (wn + c) * 64 + sl0;   // + jn*1024
  const int boff1 = (wn + c) * 64 + sl1;

  f32x4 acc[8][4] = {};

  // ---- prologue: stage tile 0 into buf0 (8 loads), drain, barrier ----
#pragma unroll
  for (int i = 0; i < 4; ++i) {
    async_copy16(gA + (size_t)i * 64 * K2, &Asb[i * 4096 + ldst]);
    async_copy16(gB + (size_t)i * 64 * K2, &Bsb[i * 4096 + ldst]);
  }
  asm volatile("s_waitcnt vmcnt(0)" ::: "memory");
  __builtin_amdgcn_s_barrier();
  asm volatile("" ::: "memory");

#pragma unroll 2
  for (int kt = 0; kt < NKT; ++kt) {
    const u16* as = &Asb[(kt & 1) * ASZ];
    const u16* bs = &Bsb[(kt & 1) * BSZ];

    // -- issue staging for tile kt+1 into the other buffers (8 loads) --
    if (kt < NKT - 1) {
      u16* sA = &Asb[((kt + 1) & 1) * ASZ];
      u16* sB = &Bsb[((kt + 1) & 1) * BSZ];
      const size_t ok = (size_t)(kt + 1) * BK;
#pragma unroll
      for (int i = 0; i < 4; ++i) {
        async_copy16(gA + ok + (size_t)i * 64 * K2, sA + i * 4096 + ldst);
        async_copy16(gB + ok + (size_t)i * 64 * K2, sB + i * 4096 + ldst);
      }
    }

    // -- B fragments for the whole K-tile (8 ds_read_b128) --
    bf16x8 bfr[2][4];
#pragma unroll
    for (int jn = 0; jn < 4; ++jn) {
      bfr[0][jn] = *(const bf16x8*)(bs + boff0 + jn * 1024);
      bfr[1][jn] = *(const bf16x8*)(bs + boff1 + jn * 1024);
    }

    // -- software-pipelined A-frag reads ∥ MFMA clusters --
    bf16x8 areg[2][2][2];   // [ph&1][half][jm] — all indices compile-time
#pragma unroll
    for (int h = 0; h < 2; ++h)
#pragma unroll
      for (int jm = 0; jm < 2; ++jm)
        areg[0][h][jm] = *(const bf16x8*)(as + (h ? aoff1 : aoff0) + jm * 1024);

#pragma unroll
    for (int ph = 0; ph < 4; ++ph) {
      if (ph < 3) {
#pragma unroll
        for (int h = 0; h < 2; ++h)
#pragma unroll
          for (int jm = 0; jm < 2; ++jm)
            areg[(ph + 1) & 1][h][jm] = *(const bf16x8*)(
                as + (h ? aoff1 : aoff0) + (2 * (ph + 1) + jm) * 1024);
      }
      __builtin_amdgcn_s_setprio(1);
#pragma unroll
      for (int jm = 0; jm < 2; ++jm)
#pragma unroll
        for (int jn = 0; jn < 4; ++jn)
          acc[2 * ph + jm][jn] = __builtin_amdgcn_mfma_f32_16x16x32_bf16(
              areg[ph & 1][0][jm], bfr[0][jn], acc[2 * ph + jm][jn], 0, 0, 0);
#pragma unroll
      for (int jm = 0; jm < 2; ++jm)
#pragma unroll
        for (int jn = 0; jn < 4; ++jn)
          acc[2 * ph + jm][jn] = __builtin_amdgcn_mfma_f32_16x16x32_bf16(
              areg[ph & 1][1][jm], bfr[1][jn], acc[2 * ph + jm][jn], 0, 0, 0);
      __builtin_amdgcn_s_setprio(0);
    }

    // -- seam: staged tile kt+1 landed everywhere; reads of kt consumed --
    if (kt < NKT - 1) {
      asm volatile("s_waitcnt vmcnt(0)" ::: "memory");
      __builtin_amdgcn_s_barrier();
      asm volatile("" ::: "memory");
    }
  }

  // ---- fused peephole-LSTM epilogue -------------------------------------
  const int u = ((n0 + wn) >> 2) + c;
  const float bf_ = bias[u];
  const float bi_ = bias[UNITS + u];
  const float bc_ = bias[2 * UNITS + u];
  const float bo_ = bias[3 * UNITS + u];
  const float pfv = pf[u], piv = pi[u], pov = po[u];
  const int mbase = m0 + wm + quad * 4;
#pragma unroll
  for (int jm = 0; jm < 8; ++jm) {
#pragma unroll
    for (int r = 0; r < 4; ++r) {
      const int b = mbase + jm * 16 + r;
      const float cp = c_prev[(size_t)b * UNITS + u];
      const float zf = acc[jm][0][r] + bf_ + pfv * cp;
      const float zi = acc[jm][1][r] + bi_ + piv * cp;
      const float zc = acc[jm][2][r] + bc_;
      const float zo = acc[jm][3][r] + bo_;
      const float fg = 1.f / (1.f + __expf(-zf));
      const float ig = 1.f / (1.f + __expf(-zi));
      const float ct = 1.f - 2.f / (__expf(2.f * zc) + 1.f);   // tanh, NaN-safe
      const float cn = fg * cp + ig * ct;
      const float og = 1.f / (1.f + __expf(-(zo + pov * cn)));
      const float hn = og * (1.f - 2.f / (__expf(2.f * cn) + 1.f));
      out_h[(size_t)b * UNITS + u] = hn;
      out_c[(size_t)b * UNITS + u] = cn;
    }
  }
}

// ---------------------------------------------------------------------------
extern "C" void kernel_launch(void* const* d_in, const int* in_sizes, int n_in,
                              void* d_out, int out_size, void* d_ws, size_t ws_size,
                              hipStream_t stream) {
  const float* x      = (const float*)d_in[0];   // [8192,1024]
  const float* c_prev = (const float*)d_in[1];   // [8192,1024]
  const float* h_prev = (const float*)d_in[2];   // [8192,1024]
  const float* W      = (const float*)d_in[3];   // [1024,4096]
  const float* U      = (const float*)d_in[4];   // [1024,4096]
  const float* bias   = (const float*)d_in[5];   // [4096]
  const float* pf     = (const float*)d_in[6];   // [1024]
  const float* pi     = (const float*)d_in[7];
  const float* po     = (const float*)d_in[8];
  float* out_h = (float*)d_out;
  float* out_c = out_h + (size_t)BATCH * UNITS;

  u16* Abf = (u16*)d_ws;                           // 32 MB
  u16* Bbf = Abf + (size_t)BATCH * K2;             // 16 MB

  cast_fused_kernel<<<6144, 256, 0, stream>>>(x, h_prev, W, U, Abf, Bbf);
  lstm_gemm_kernel<<<dim3(N4 / BN, BATCH / BM), 512, 0, stream>>>(
      Abf, Bbf, bias, c_prev, pf, pi, po, out_h, out_c);
}